// Round 14
// baseline (187.809 us; speedup 1.0000x reference)
//
#include <hip/hip_runtime.h>
#include <math.h>

#define DDIM 4096
#define EDIM 64
#define NROWS 16384
#define MBLK 32
#define NKT 64            // K-tiles of 64
#define TOPK_K 8
#define DIGIT_BIAS 0x00808080

typedef int   i32x4 __attribute__((ext_vector_type(4)));
typedef float f32x4 __attribute__((ext_vector_type(4)));

// signed-digit int8 decomposition: bytes of (v+BIAS)^BIAS are signed digits
// d_p with v = sum d_p * 256^p (exact for |v| < 2^31 - 2^23)
__device__ __forceinline__ int digits_rn(float f) {
  int v = __float2int_rn(f);
  return (v + DIGIT_BIAS) ^ DIGIT_BIAS;
}
__device__ __forceinline__ int digits_tz(float f) {
  int v = (int)f;                    // trunc cvt; verified R9/R10/R13
  return (v + DIGIT_BIAS) ^ DIGIT_BIAS;
}

__device__ __forceinline__ unsigned perm_b32(unsigned a, unsigned b, unsigned sel) {
#if __has_builtin(__builtin_amdgcn_perm)
  return __builtin_amdgcn_perm(a, b, sel);
#else
  union { unsigned u[2]; unsigned char c[8]; } s; s.u[0] = b; s.u[1] = a;
  unsigned r = 0;
  for (int i = 0; i < 4; ++i) r |= (unsigned)s.c[(sel >> (8*i)) & 7] << (8*i);
  return r;
#endif
}

// convert 4 f32 (group g) -> byte-group g of 4 digit-plane regs (x * 2^25)
__device__ __forceinline__ void cvtg(const f32x4 v, i32x4 (&An)[4], int g) {
  unsigned f0 = (unsigned)digits_tz(v[0] * 33554432.0f);
  unsigned f1 = (unsigned)digits_tz(v[1] * 33554432.0f);
  unsigned f2 = (unsigned)digits_tz(v[2] * 33554432.0f);
  unsigned f3 = (unsigned)digits_tz(v[3] * 33554432.0f);
  unsigned zl01 = perm_b32(f1, f0, 0x05010400u);
  unsigned zh01 = perm_b32(f1, f0, 0x07030602u);
  unsigned zl23 = perm_b32(f3, f2, 0x05010400u);
  unsigned zh23 = perm_b32(f3, f2, 0x07030602u);
  An[0][g] = (int)perm_b32(zl23, zl01, 0x05040100u);
  An[1][g] = (int)perm_b32(zl23, zl01, 0x07060302u);
  An[2][g] = (int)perm_b32(zh23, zh01, 0x05040100u);
  An[3][g] = (int)perm_b32(zh23, zh01, 0x07060302u);
}

// 13 MFMAs into 5 weight-class accs, round-robin (verified exact R9/R10)
__device__ __forceinline__ void mfma13(const i32x4 (&a)[4], const i32x4 (&b)[4],
                                       i32x4 (&c)[5]) {
  c[0] = __builtin_amdgcn_mfma_i32_16x16x64_i8(a[3], b[3], c[0], 0, 0, 0);
  c[1] = __builtin_amdgcn_mfma_i32_16x16x64_i8(a[3], b[2], c[1], 0, 0, 0);
  c[2] = __builtin_amdgcn_mfma_i32_16x16x64_i8(a[3], b[1], c[2], 0, 0, 0);
  c[3] = __builtin_amdgcn_mfma_i32_16x16x64_i8(a[3], b[0], c[3], 0, 0, 0);
  c[4] = __builtin_amdgcn_mfma_i32_16x16x64_i8(a[2], b[0], c[4], 0, 0, 0);
  c[1] = __builtin_amdgcn_mfma_i32_16x16x64_i8(a[2], b[3], c[1], 0, 0, 0);
  c[2] = __builtin_amdgcn_mfma_i32_16x16x64_i8(a[2], b[2], c[2], 0, 0, 0);
  c[3] = __builtin_amdgcn_mfma_i32_16x16x64_i8(a[2], b[1], c[3], 0, 0, 0);
  c[4] = __builtin_amdgcn_mfma_i32_16x16x64_i8(a[1], b[1], c[4], 0, 0, 0);
  c[2] = __builtin_amdgcn_mfma_i32_16x16x64_i8(a[1], b[3], c[2], 0, 0, 0);
  c[3] = __builtin_amdgcn_mfma_i32_16x16x64_i8(a[1], b[2], c[3], 0, 0, 0);
  c[4] = __builtin_amdgcn_mfma_i32_16x16x64_i8(a[0], b[2], c[4], 0, 0, 0);
  c[3] = __builtin_amdgcn_mfma_i32_16x16x64_i8(a[0], b[3], c[3], 0, 0, 0);
}

// ---------------------------------------------------------------------------
// Wr [4096][64] f32 -> 4 int8 digit planes (w*2^36), fragment-major,
// 64-K-tile granular. (verified R4-R10: idx exact) — UNCHANGED
// ---------------------------------------------------------------------------
__global__ __launch_bounds__(256) void wr_convert(const float* __restrict__ Wr,
                                                  char* __restrict__ wl8) {
  int t = blockIdx.x * 256 + threadIdx.x;
  int e = t & 63, k16 = t >> 6;
  int kt64 = k16 >> 2, kgg = k16 & 3, nf = e >> 4, col = e & 15;
  int D[16];
  #pragma unroll
  for (int j = 0; j < 16; ++j)
    D[j] = digits_rn(Wr[(size_t)(k16 * 16 + j) * EDIM + e] * 68719476736.0f);
  #pragma unroll
  for (int pl = 0; pl < 4; ++pl) {
    unsigned wv[4];
    #pragma unroll
    for (int g = 0; g < 4; ++g)
      wv[g] = ((unsigned)((D[4*g+0] >> (8*pl)) & 255))
            | ((unsigned)((D[4*g+1] >> (8*pl)) & 255) << 8)
            | ((unsigned)((D[4*g+2] >> (8*pl)) & 255) << 16)
            | ((unsigned)((D[4*g+3] >> (8*pl)) & 255) << 24);
    i32x4 val = {(int)wv[0], (int)wv[1], (int)wv[2], (int)wv[3]};
    *(i32x4*)(wl8 + (size_t)pl * 262144 + (size_t)(kt64 * 4 + nf) * 1024
              + (size_t)(kgg * 16 + col) * 16) = val;
  }
}

// ---------------------------------------------------------------------------
// Fused exact router — barrier-free, LDS-free main loop (R9's verified
// addressing), asm-issued batched loads with homogeneous vmcnt counting:
// batch(t) = 8 x global_load_dwordx4 (4 x-frag + 4 B-plane); batches t,t+1
// in flight; vmcnt(8) == "batch t landed". Consume-then-reissue ordering.
// 512 blocks x 512 threads (2 blk/CU, 4 waves/SIMD); 8 waves = 2mw x 4nw.
// ---------------------------------------------------------------------------
__global__ __launch_bounds__(512, 4) void router_fused(
    const float* __restrict__ x, const char* __restrict__ wl8,
    const float* __restrict__ br,
    float* __restrict__ out_scores, float* __restrict__ out_idx) {
  __shared__ double ls[MBLK * EDIM];   // 16 KiB, epilogue only

  const int tid  = threadIdx.x;
  const int lane = tid & 63;
  const int w    = tid >> 6;
  const int mw   = w >> 2;
  const int nw   = w & 3;
  const int kg   = lane >> 4;
  const int row0 = blockIdx.x * MBLK;
  const int row_l = mw * 16 + (lane & 15);
  const float bias = br[nw * 16 + (lane & 15)];

  const char* xr = (const char*)x + ((size_t)(row0 + row_l)) * (DDIM * 4) + kg * 64;
  const char* wb = wl8 + (size_t)nw * 1024 + (size_t)lane * 16;

  i32x4 acc[5] = {};                // digit-weight classes s6..s2
  f32x4 X0[4], X1[4];
  i32x4 B0[4], B1[4];
  i32x4 A[4];

  // one batch: 8 loads in fixed order (x c0..c3, B p0..p3)
#define BATCH(XS, BS, TV) do {                                                       \
    const char* _xp = xr + (size_t)(TV) * 256;                                       \
    const char* _bp = wb + (size_t)(TV) * 4096;                                      \
    asm volatile("global_load_dwordx4 %0, %1, off"           : "=&v"(XS[0]) : "v"(_xp)); \
    asm volatile("global_load_dwordx4 %0, %1, off offset:16" : "=&v"(XS[1]) : "v"(_xp)); \
    asm volatile("global_load_dwordx4 %0, %1, off offset:32" : "=&v"(XS[2]) : "v"(_xp)); \
    asm volatile("global_load_dwordx4 %0, %1, off offset:48" : "=&v"(XS[3]) : "v"(_xp)); \
    asm volatile("global_load_dwordx4 %0, %1, off" : "=&v"(BS[0]) : "v"(_bp));           \
    asm volatile("global_load_dwordx4 %0, %1, off" : "=&v"(BS[1]) : "v"(_bp + 262144));  \
    asm volatile("global_load_dwordx4 %0, %1, off" : "=&v"(BS[2]) : "v"(_bp + 524288));  \
    asm volatile("global_load_dwordx4 %0, %1, off" : "=&v"(BS[3]) : "v"(_bp + 786432));  \
  } while (0)

#define CONSUME(XS, BS) do {                                                         \
    cvtg(XS[0], A, 0); cvtg(XS[1], A, 1); cvtg(XS[2], A, 2); cvtg(XS[3], A, 3);      \
    mfma13(A, BS, acc);                                                              \
  } while (0)

  BATCH(X0, B0, 0);
  BATCH(X1, B1, 1);
  for (int t = 0; t < 60; t += 2) {
    asm volatile("s_waitcnt vmcnt(8)" ::: "memory");
    __builtin_amdgcn_sched_barrier(0);
    CONSUME(X0, B0);
    BATCH(X0, B0, t + 2);
    asm volatile("s_waitcnt vmcnt(8)" ::: "memory");
    __builtin_amdgcn_sched_barrier(0);
    CONSUME(X1, B1);
    BATCH(X1, B1, t + 3);
  }
  // t=60,61 consumed with issue of 62,63 done above (t=58 iter issued 60,61;
  // t=60 loop iter would issue 62,63) -> handle 60..63 explicitly:
  asm volatile("s_waitcnt vmcnt(8)" ::: "memory");
  __builtin_amdgcn_sched_barrier(0);
  CONSUME(X0, B0);                 // tile 60
  BATCH(X0, B0, 62);
  asm volatile("s_waitcnt vmcnt(8)" ::: "memory");
  __builtin_amdgcn_sched_barrier(0);
  CONSUME(X1, B1);                 // tile 61
  BATCH(X1, B1, 63);
  asm volatile("s_waitcnt vmcnt(8)" ::: "memory");
  __builtin_amdgcn_sched_barrier(0);
  CONSUME(X0, B0);                 // tile 62
  asm volatile("s_waitcnt vmcnt(0)" ::: "memory");
  __builtin_amdgcn_sched_barrier(0);
  CONSUME(X1, B1);                 // tile 63

  // ---- epilogue: fp64 combine (class s: 2^(8s-61)), top-8, sparse softmax ----
  {
    int cc = nw * 16 + (lane & 15);
    #pragma unroll
    for (int j = 0; j < 4; ++j) {
      int r = mw * 16 + (lane >> 4) * 4 + j;   // C/D: row=(lane>>4)*4+reg
      ls[r * 64 + cc] = (double)acc[0][j] * 0x1p-13 + (double)acc[1][j] * 0x1p-21
                      + (double)acc[2][j] * 0x1p-29 + (double)acc[3][j] * 0x1p-37
                      + (double)acc[4][j] * 0x1p-45 + (double)bias;
    }
  }
  __syncthreads();

  for (int rr = 0; rr < 4; ++rr) {
    int r = w * 4 + rr;
    double v0 = ls[r * 64 + lane];
    double cur = v0;
    bool sel  = false;
    int myidx = 0;
    double maxv = 0.0;
    #pragma unroll
    for (int k = 0; k < TOPK_K; ++k) {
      double bv = cur;
      int    bi = lane;
      #pragma unroll
      for (int off = 32; off; off >>= 1) {
        double ov = __shfl_xor(bv, off);
        int    oi = __shfl_xor(bi, off);
        if (ov > bv || (ov == bv && oi < bi)) { bv = ov; bi = oi; }
      }
      if (k == 0) maxv = bv;
      if (lane == k) myidx = bi;
      if (lane == bi) { cur = -__builtin_inf(); sel = true; }
    }
    float pv = sel ? expf((float)(v0 - maxv)) : 0.f;
    float ssum = pv;
    #pragma unroll
    for (int off = 32; off; off >>= 1) ssum += __shfl_xor(ssum, off);

    size_t rg = (size_t)row0 + r;
    out_scores[rg * 64 + lane] = pv / ssum;
    if (lane < TOPK_K) out_idx[rg * 8 + lane] = (float)myidx;
  }
}

extern "C" void kernel_launch(void* const* d_in, const int* in_sizes, int n_in,
                              void* d_out, int out_size, void* d_ws, size_t ws_size,
                              hipStream_t stream) {
  const float* x  = (const float*)d_in[0];
  const float* Wr = (const float*)d_in[1];
  const float* br = (const float*)d_in[2];
  // d_in[3] (Wn), d_in[4] (bn): dead code in the reference — intentionally unused.

  char* wl8 = (char*)d_ws;                          // 4 planes x 256 KiB = 1 MiB
  float* out_scores = (float*)d_out;
  float* out_idx    = out_scores + (size_t)NROWS * EDIM;

  wr_convert<<<64, 256, 0, stream>>>(Wr, wl8);
  router_fused<<<NROWS / MBLK, 512, 0, stream>>>(x, wl8, br, out_scores, out_idx);
}

// Round 15
// 184.307 us; speedup vs baseline: 1.0190x; 1.0190x over previous
//
#include <hip/hip_runtime.h>
#include <math.h>

#define DDIM 4096
#define EDIM 64
#define NROWS 16384
#define MBLK 32
#define NKT 64            // K-tiles of 64
#define TOPK_K 8
#define DIGIT_BIAS 0x00808080

typedef int   i32x4 __attribute__((ext_vector_type(4)));
typedef float f32x4 __attribute__((ext_vector_type(4)));

// signed-digit int8 decomposition: bytes of (v+BIAS)^BIAS are signed digits
// d_p with v = sum d_p * 256^p (exact for |v| < 2^31 - 2^23)
__device__ __forceinline__ int digits_rn(float f) {
  int v = __float2int_rn(f);
  return (v + DIGIT_BIAS) ^ DIGIT_BIAS;
}
__device__ __forceinline__ int digits_tz(float f) {
  int v = (int)f;                    // trunc cvt; verified R9/R10/R13
  return (v + DIGIT_BIAS) ^ DIGIT_BIAS;
}

__device__ __forceinline__ unsigned perm_b32(unsigned a, unsigned b, unsigned sel) {
#if __has_builtin(__builtin_amdgcn_perm)
  return __builtin_amdgcn_perm(a, b, sel);
#else
  union { unsigned u[2]; unsigned char c[8]; } s; s.u[0] = b; s.u[1] = a;
  unsigned r = 0;
  for (int i = 0; i < 4; ++i) r |= (unsigned)s.c[(sel >> (8*i)) & 7] << (8*i);
  return r;
#endif
}

// convert 4 f32 (group g) -> byte-group g of 4 digit-plane regs (x * 2^25)
__device__ __forceinline__ void cvtg(const f32x4 v, i32x4 (&An)[4], int g) {
  unsigned f0 = (unsigned)digits_tz(v[0] * 33554432.0f);
  unsigned f1 = (unsigned)digits_tz(v[1] * 33554432.0f);
  unsigned f2 = (unsigned)digits_tz(v[2] * 33554432.0f);
  unsigned f3 = (unsigned)digits_tz(v[3] * 33554432.0f);
  unsigned zl01 = perm_b32(f1, f0, 0x05010400u);
  unsigned zh01 = perm_b32(f1, f0, 0x07030602u);
  unsigned zl23 = perm_b32(f3, f2, 0x05010400u);
  unsigned zh23 = perm_b32(f3, f2, 0x07030602u);
  An[0][g] = (int)perm_b32(zl23, zl01, 0x05040100u);
  An[1][g] = (int)perm_b32(zl23, zl01, 0x07060302u);
  An[2][g] = (int)perm_b32(zh23, zh01, 0x05040100u);
  An[3][g] = (int)perm_b32(zh23, zh01, 0x07060302u);
}

// 13 MFMAs into 5 weight-class accs, round-robin (verified exact R9/R10)
__device__ __forceinline__ void mfma13(const i32x4 (&a)[4], const i32x4 (&b)[4],
                                       i32x4 (&c)[5]) {
  c[0] = __builtin_amdgcn_mfma_i32_16x16x64_i8(a[3], b[3], c[0], 0, 0, 0);
  c[1] = __builtin_amdgcn_mfma_i32_16x16x64_i8(a[3], b[2], c[1], 0, 0, 0);
  c[2] = __builtin_amdgcn_mfma_i32_16x16x64_i8(a[3], b[1], c[2], 0, 0, 0);
  c[3] = __builtin_amdgcn_mfma_i32_16x16x64_i8(a[3], b[0], c[3], 0, 0, 0);
  c[4] = __builtin_amdgcn_mfma_i32_16x16x64_i8(a[2], b[0], c[4], 0, 0, 0);
  c[1] = __builtin_amdgcn_mfma_i32_16x16x64_i8(a[2], b[3], c[1], 0, 0, 0);
  c[2] = __builtin_amdgcn_mfma_i32_16x16x64_i8(a[2], b[2], c[2], 0, 0, 0);
  c[3] = __builtin_amdgcn_mfma_i32_16x16x64_i8(a[2], b[1], c[3], 0, 0, 0);
  c[4] = __builtin_amdgcn_mfma_i32_16x16x64_i8(a[1], b[1], c[4], 0, 0, 0);
  c[2] = __builtin_amdgcn_mfma_i32_16x16x64_i8(a[1], b[3], c[2], 0, 0, 0);
  c[3] = __builtin_amdgcn_mfma_i32_16x16x64_i8(a[1], b[2], c[3], 0, 0, 0);
  c[4] = __builtin_amdgcn_mfma_i32_16x16x64_i8(a[0], b[2], c[4], 0, 0, 0);
  c[3] = __builtin_amdgcn_mfma_i32_16x16x64_i8(a[0], b[3], c[3], 0, 0, 0);
}

// ---------------------------------------------------------------------------
// Wr [4096][64] f32 -> 4 int8 digit planes (w*2^36), fragment-major,
// 64-K-tile granular. (verified R4-R14: idx exact) — UNCHANGED
// ---------------------------------------------------------------------------
__global__ __launch_bounds__(256) void wr_convert(const float* __restrict__ Wr,
                                                  char* __restrict__ wl8) {
  int t = blockIdx.x * 256 + threadIdx.x;
  int e = t & 63, k16 = t >> 6;
  int kt64 = k16 >> 2, kgg = k16 & 3, nf = e >> 4, col = e & 15;
  int D[16];
  #pragma unroll
  for (int j = 0; j < 16; ++j)
    D[j] = digits_rn(Wr[(size_t)(k16 * 16 + j) * EDIM + e] * 68719476736.0f);
  #pragma unroll
  for (int pl = 0; pl < 4; ++pl) {
    unsigned wv[4];
    #pragma unroll
    for (int g = 0; g < 4; ++g)
      wv[g] = ((unsigned)((D[4*g+0] >> (8*pl)) & 255))
            | ((unsigned)((D[4*g+1] >> (8*pl)) & 255) << 8)
            | ((unsigned)((D[4*g+2] >> (8*pl)) & 255) << 16)
            | ((unsigned)((D[4*g+3] >> (8*pl)) & 255) << 24);
    i32x4 val = {(int)wv[0], (int)wv[1], (int)wv[2], (int)wv[3]};
    *(i32x4*)(wl8 + (size_t)pl * 262144 + (size_t)(kt64 * 4 + nf) * 1024
              + (size_t)(kgg * 16 + col) * 16) = val;
  }
}

// ---------------------------------------------------------------------------
// Fused exact router — R9's barrier-free/LDS-free main loop, with the
// occupancy target FORCED to 4 waves/EU (amdgpu_waves_per_eu(4,4)): gives
// the allocator a 128-VGPR budget so the 2-tile operand lookahead stays in
// registers instead of being sunk/rematerialized (R5-R14: VGPR pinned <=72,
// loads sunk to use, 3x VALU bloat). Single-variable experiment vs R9.
// 512 blocks x 512 threads; 32 rows/block; 8 waves = 2mw x 4nw.
// ---------------------------------------------------------------------------
__global__ __launch_bounds__(512)
__attribute__((amdgpu_waves_per_eu(4, 4)))
void router_fused(
    const float* __restrict__ x, const char* __restrict__ wl8,
    const float* __restrict__ br,
    float* __restrict__ out_scores, float* __restrict__ out_idx) {
  __shared__ double ls[MBLK * EDIM];   // 16 KiB, epilogue only

  const int tid  = threadIdx.x;
  const int lane = tid & 63;
  const int w    = tid >> 6;
  const int mw   = w >> 2;
  const int nw   = w & 3;
  const int kg   = lane >> 4;
  const int row0 = blockIdx.x * MBLK;
  const int row_l = mw * 16 + (lane & 15);
  const float bias = br[nw * 16 + (lane & 15)];

  // lane-invariant bases: x (lane's own row + kg slot), W frag chunk
  const char* xr = (const char*)x + ((size_t)(row0 + row_l)) * (DDIM * 4) + kg * 64;
  const char* wr = wl8 + (size_t)nw * 1024 + (size_t)lane * 16;

  i32x4 acc[5] = {};                // digit-weight classes s6..s2
  f32x4 X0[4], X1[4];
  i32x4 B0[4], B1[4];
  i32x4 A[4];

  auto loadX = [&](int t, f32x4 (&X)[4]) {
    const char* p = xr + (size_t)t * 256;
    #pragma unroll
    for (int c = 0; c < 4; ++c) X[c] = *(const f32x4*)(p + c * 16);
  };
  auto loadB = [&](int t, i32x4 (&B)[4]) {
    const char* p = wr + (size_t)t * 4096;
    #pragma unroll
    for (int pl = 0; pl < 4; ++pl)
      B[pl] = *(const i32x4*)(p + (size_t)pl * 262144);
  };
  auto consume = [&](const f32x4 (&X)[4], const i32x4 (&B)[4]) {
    cvtg(X[0], A, 0); cvtg(X[1], A, 1); cvtg(X[2], A, 2); cvtg(X[3], A, 3);
    mfma13(A, B, acc);
  };

  // prologue: 2 tiles in flight
  loadB(0, B0); loadX(0, X0);
  loadB(1, B1); loadX(1, X1);

  for (int t = 0; t < NKT; t += 2) {
    consume(X0, B0);
    if (t + 2 < NKT) { loadB(t + 2, B0); loadX(t + 2, X0); }
    consume(X1, B1);
    if (t + 3 < NKT) { loadB(t + 3, B1); loadX(t + 3, X1); }
  }

  // ---- epilogue: fp64 combine (class s: 2^(8s-61)), top-8, sparse softmax ----
  {
    int cc = nw * 16 + (lane & 15);
    #pragma unroll
    for (int j = 0; j < 4; ++j) {
      int r = mw * 16 + (lane >> 4) * 4 + j;   // C/D: row=(lane>>4)*4+reg
      ls[r * 64 + cc] = (double)acc[0][j] * 0x1p-13 + (double)acc[1][j] * 0x1p-21
                      + (double)acc[2][j] * 0x1p-29 + (double)acc[3][j] * 0x1p-37
                      + (double)acc[4][j] * 0x1p-45 + (double)bias;
    }
  }
  __syncthreads();

  for (int rr = 0; rr < 4; ++rr) {
    int r = w * 4 + rr;
    double v0 = ls[r * 64 + lane];
    double cur = v0;
    bool sel  = false;
    int myidx = 0;
    double maxv = 0.0;
    #pragma unroll
    for (int k = 0; k < TOPK_K; ++k) {
      double bv = cur;
      int    bi = lane;
      #pragma unroll
      for (int off = 32; off; off >>= 1) {
        double ov = __shfl_xor(bv, off);
        int    oi = __shfl_xor(bi, off);
        if (ov > bv || (ov == bv && oi < bi)) { bv = ov; bi = oi; }
      }
      if (k == 0) maxv = bv;
      if (lane == k) myidx = bi;
      if (lane == bi) { cur = -__builtin_inf(); sel = true; }
    }
    float pv = sel ? expf((float)(v0 - maxv)) : 0.f;
    float ssum = pv;
    #pragma unroll
    for (int off = 32; off; off >>= 1) ssum += __shfl_xor(ssum, off);

    size_t rg = (size_t)row0 + r;
    out_scores[rg * 64 + lane] = pv / ssum;
    if (lane < TOPK_K) out_idx[rg * 8 + lane] = (float)myidx;
  }
}

extern "C" void kernel_launch(void* const* d_in, const int* in_sizes, int n_in,
                              void* d_out, int out_size, void* d_ws, size_t ws_size,
                              hipStream_t stream) {
  const float* x  = (const float*)d_in[0];
  const float* Wr = (const float*)d_in[1];
  const float* br = (const float*)d_in[2];
  // d_in[3] (Wn), d_in[4] (bn): dead code in the reference — intentionally unused.

  char* wl8 = (char*)d_ws;                          // 4 planes x 256 KiB = 1 MiB
  float* out_scores = (float*)d_out;
  float* out_idx    = out_scores + (size_t)NROWS * EDIM;

  wr_convert<<<64, 256, 0, stream>>>(Wr, wl8);
  router_fused<<<NROWS / MBLK, 512, 0, stream>>>(x, wl8, br, out_scores, out_idx);
}